// Round 3
// 697.701 us; speedup vs baseline: 1.1187x; 1.1187x over previous
//
#include <hip/hip_runtime.h>

// Problem: B=4, H=16, S=1024, D=64, fp32.
//   scores2 = scale * Q @ (mask @ K)^T   (reassociated: 4.5x fewer FLOPs)
//   attn    = softmax(scores2)
//   context = attn @ V
// The two big GEMMs (mask@K and attn@V) run on the MFMA pipe via bf16x3
// split products (A=Ah+Al, B=Bh+Bl, C ~= AhBh + AhBl + AlBh).
// R1 fix: B-tile staging wrote only 8 of each 16-bf16 slot -> uninitialized
// LDS -> NaN. Now two uint4 writes per slot.
// R2: unchanged resubmit (R1 run died on container acquisition, no signal).

#define BH   64
#define S    1024
#define D    64
#define SCALE 0.125f

typedef __attribute__((ext_vector_type(8))) short  short8;   // 8 bf16 = 4 VGPR
typedef __attribute__((ext_vector_type(4))) float  f32x4;    // MFMA C/D

static __device__ __forceinline__ unsigned short f2bf(float x) {
    unsigned int u = __float_as_uint(x);
    return (unsigned short)((u + 0x7fffu + ((u >> 16) & 1u)) >> 16);  // RNE
}
static __device__ __forceinline__ float bf2f(unsigned short h) {
    return __uint_as_float(((unsigned int)h) << 16);
}

static __device__ __forceinline__ void fma4(float4& a, float s, const float4& b) {
    a.x = fmaf(s, b.x, a.x);
    a.y = fmaf(s, b.y, a.y);
    a.z = fmaf(s, b.z, a.z);
    a.w = fmaf(s, b.w, a.w);
}

// ---------------------------------------------------------------------------
// Pre-pass: X in {K,V} ([bh][S][D] f32) -> bf16 hi/lo of X^T: [bh][D][S].
__global__ __launch_bounds__(256) void transpose_split(
        const float* __restrict__ K, const float* __restrict__ V,
        unsigned short* __restrict__ Kth, unsigned short* __restrict__ Ktl,
        unsigned short* __restrict__ Vth, unsigned short* __restrict__ Vtl) {
    const int bh = blockIdx.y;
    const int t0 = blockIdx.x * 64;
    const float* src      = (blockIdx.z == 0) ? K   : V;
    unsigned short* dsth  = (blockIdx.z == 0) ? Kth : Vth;
    unsigned short* dstl  = (blockIdx.z == 0) ? Ktl : Vtl;
    const int tid = threadIdx.x;

    __shared__ float T[64][68];
    {
        const int r = tid >> 4;
        const int c = (tid & 15) * 4;
#pragma unroll
        for (int i = 0; i < 4; i++) {
            float4 v = *(const float4*)&src[((size_t)bh * S + t0 + r + 16 * i) * D + c];
            *(float4*)&T[r + 16 * i][c] = v;
        }
    }
    __syncthreads();

    const int d = tid >> 2;          // 0..63  (output row = d)
    const int u = (tid & 3) * 16;    // 16 t-values per thread
    unsigned int hw[8], lw[8];
#pragma unroll
    for (int j = 0; j < 8; j++) {
        float x0 = T[u + 2 * j + 0][d];
        float x1 = T[u + 2 * j + 1][d];
        unsigned short h0 = f2bf(x0), h1 = f2bf(x1);
        unsigned short l0 = f2bf(x0 - bf2f(h0)), l1 = f2bf(x1 - bf2f(h1));
        hw[j] = (unsigned)h0 | ((unsigned)h1 << 16);
        lw[j] = (unsigned)l0 | ((unsigned)l1 << 16);
    }
    const size_t o = ((size_t)bh * D + d) * S + t0 + u;
    uint4 hv0 = {hw[0], hw[1], hw[2], hw[3]};
    uint4 hv1 = {hw[4], hw[5], hw[6], hw[7]};
    uint4 lv0 = {lw[0], lw[1], lw[2], lw[3]};
    uint4 lv1 = {lw[4], lw[5], lw[6], lw[7]};
    *(uint4*)&dsth[o]     = hv0;
    *(uint4*)&dsth[o + 8] = hv1;
    *(uint4*)&dstl[o]     = lv0;
    *(uint4*)&dstl[o + 8] = lv1;
}

// ---------------------------------------------------------------------------
// C[bh] = A[bh] @ B[bh] with A [S][S] f32 (split inline), B given pre-split
// transposed ([D][S] bf16 hi/lo). Tile 64x64, 4 waves (2x2), mfma 16x16x32.
// TRANS_OUT: C stored [D][S] (for M2T), else [S][D].
template <bool TRANS_OUT>
__global__ __launch_bounds__(256) void gemm_mfma(
        const float* __restrict__ A,
        const unsigned short* __restrict__ Bth,
        const unsigned short* __restrict__ Btl,
        float* __restrict__ C) {
    const int bh  = blockIdx.y;
    const int u0  = blockIdx.x * 64;
    const int tid = threadIdx.x;

    // Ah/Al/Bh/Bl tiles: [64 rows][64 bf16] = 128 B rows, XOR-swizzled 16B
    // slots (byte ^= (row&7)<<4) to break the 128B-stride bank aliasing.
    __shared__ __align__(16) char lds[4 * 8192];
    char* Ah = lds;
    char* Al = lds + 8192;
    char* Bh = lds + 16384;
    char* Bl = lds + 24576;

    const float*          Ab  = A   + (size_t)bh * S * S + (size_t)u0 * S;
    const unsigned short* Bhb = Bth + (size_t)bh * D * S;
    const unsigned short* Blb = Btl + (size_t)bh * D * S;

    const int wid = tid >> 6;
    const int l   = tid & 63;
    const int wm  = wid >> 1, wn = wid & 1;   // wave -> 32x32 quadrant
    const int lr  = l & 15,   lg = l >> 4;    // fragment row / k-group

    f32x4 zero = {0.f, 0.f, 0.f, 0.f};
    f32x4 acc[2][2];
    acc[0][0] = zero; acc[0][1] = zero; acc[1][0] = zero; acc[1][1] = zero;

    const int ar = tid >> 4;            // A staging: row 0..15 (+16i)
    const int ac = (tid & 15) * 4;      //            4 floats
    const int br = tid >> 2;            // B staging: row 0..63
    const int bc = (tid & 3) * 16;      //            16 bf16 (two uint4)

    for (int t0 = 0; t0 < S; t0 += 64) {
        // stage A tile (f32 -> bf16 hi/lo), rows u0.., cols t0..
#pragma unroll
        for (int i = 0; i < 4; i++) {
            const int row = ar + 16 * i;
            float4 v = *(const float4*)&Ab[(size_t)row * S + t0 + ac];
            ushort4 h4, l4;
            h4.x = f2bf(v.x); l4.x = f2bf(v.x - bf2f(h4.x));
            h4.y = f2bf(v.y); l4.y = f2bf(v.y - bf2f(h4.y));
            h4.z = f2bf(v.z); l4.z = f2bf(v.z - bf2f(h4.z));
            h4.w = f2bf(v.w); l4.w = f2bf(v.w - bf2f(h4.w));
            const int off = (row * 128 + ac * 2) ^ ((row & 7) << 4);
            *(ushort4*)(Ah + off) = h4;
            *(ushort4*)(Al + off) = l4;
        }
        // stage B tile (already bf16, already transposed): rows = outcol d.
        // 16 bf16 per thread = TWO uint4.
        {
            const size_t g   = (size_t)br * S + t0 + bc;
            const int base   = br * 128 + bc * 2;
            const int sw     = (br & 7) << 4;
            *(uint4*)(Bh + ((base     ) ^ sw)) = *(const uint4*)&Bhb[g];
            *(uint4*)(Bh + ((base + 16) ^ sw)) = *(const uint4*)&Bhb[g + 8];
            *(uint4*)(Bl + ((base     ) ^ sw)) = *(const uint4*)&Blb[g];
            *(uint4*)(Bl + ((base + 16) ^ sw)) = *(const uint4*)&Blb[g + 8];
        }
        __syncthreads();

#pragma unroll
        for (int kk = 0; kk < 2; kk++) {  // two K=32 sub-steps
            short8 a_h[2], a_l[2], b_h[2], b_l[2];
#pragma unroll
            for (int mi = 0; mi < 2; mi++) {
                const int row = wm * 32 + mi * 16 + lr;
                const int off = (row * 128 + kk * 64 + lg * 16) ^ ((row & 7) << 4);
                a_h[mi] = *(const short8*)(Ah + off);
                a_l[mi] = *(const short8*)(Al + off);
            }
#pragma unroll
            for (int nj = 0; nj < 2; nj++) {
                const int col = wn * 32 + nj * 16 + lr;
                const int off = (col * 128 + kk * 64 + lg * 16) ^ ((col & 7) << 4);
                b_h[nj] = *(const short8*)(Bh + off);
                b_l[nj] = *(const short8*)(Bl + off);
            }
#pragma unroll
            for (int mi = 0; mi < 2; mi++)
#pragma unroll
                for (int nj = 0; nj < 2; nj++) {
                    acc[mi][nj] = __builtin_amdgcn_mfma_f32_16x16x32_bf16(
                        a_h[mi], b_h[nj], acc[mi][nj], 0, 0, 0);
                    acc[mi][nj] = __builtin_amdgcn_mfma_f32_16x16x32_bf16(
                        a_h[mi], b_l[nj], acc[mi][nj], 0, 0, 0);
                    acc[mi][nj] = __builtin_amdgcn_mfma_f32_16x16x32_bf16(
                        a_l[mi], b_h[nj], acc[mi][nj], 0, 0, 0);
                }
        }
        __syncthreads();
    }

    if (TRANS_OUT) {
        // transpose through LDS (reuse tile space) for coalesced [D][S] store
        float (*Cs)[68] = (float(*)[68])lds;
#pragma unroll
        for (int mi = 0; mi < 2; mi++)
#pragma unroll
            for (int nj = 0; nj < 2; nj++) {
                const int col = wn * 32 + nj * 16 + lr;
#pragma unroll
                for (int r = 0; r < 4; r++) {
                    const int row = wm * 32 + mi * 16 + lg * 4 + r;
                    Cs[row][col] = acc[mi][nj][r];
                }
            }
        __syncthreads();
        float* Cb = C + (size_t)bh * D * S;  // [d][u]
        const int d  = tid >> 2;
        const int ub = (tid & 3) * 16;
#pragma unroll
        for (int g = 0; g < 4; g++) {
            float4 v;
            v.x = Cs[ub + 4 * g + 0][d];
            v.y = Cs[ub + 4 * g + 1][d];
            v.z = Cs[ub + 4 * g + 2][d];
            v.w = Cs[ub + 4 * g + 3][d];
            *(float4*)&Cb[(size_t)d * S + u0 + ub + 4 * g] = v;
        }
    } else {
        float* Cb = C + (size_t)bh * S * D;  // [u][d]
#pragma unroll
        for (int mi = 0; mi < 2; mi++)
#pragma unroll
            for (int nj = 0; nj < 2; nj++) {
                const int col = wn * 32 + nj * 16 + lr;
#pragma unroll
                for (int r = 0; r < 4; r++) {
                    const int row = u0 + wm * 32 + mi * 16 + lg * 4 + r;
                    Cb[(size_t)row * D + col] = acc[mi][nj][r];
                }
            }
    }
}

// ---------------------------------------------------------------------------
// logits[s,u] = scale * sum_d Q[s,d] * M2T[d][u]; row softmax; write attn.
__global__ __launch_bounds__(256) void logits_softmax(const float* __restrict__ Q,
                                                      const float* __restrict__ M2T,
                                                      float* __restrict__ attn) {
    const int bh  = blockIdx.y;
    const int s0  = blockIdx.x * 16;
    const int tid = threadIdx.x;
    const int w   = tid >> 6;
    const int l   = tid & 63;

    __shared__ float Qs[16][68];
    {
        const int r = tid >> 4;
        const int c = (tid & 15) * 4;
        float4 v = *(const float4*)&Q[((size_t)bh * S + s0 + r) * D + c];
        v.x *= SCALE; v.y *= SCALE; v.z *= SCALE; v.w *= SCALE;
        *(float4*)&Qs[r][c] = v;
    }
    __syncthreads();

    float4 acc[4][4];
#pragma unroll
    for (int r = 0; r < 4; r++)
#pragma unroll
        for (int c = 0; c < 4; c++) acc[r][c] = make_float4(0.f, 0.f, 0.f, 0.f);

    const float* M2b = M2T + (size_t)bh * D * S;

#pragma unroll 4
    for (int d = 0; d < D; d++) {
        const float* row = M2b + (size_t)d * S;
        float4 m0 = *(const float4*)&row[0 * 256 + 4 * l];
        float4 m1 = *(const float4*)&row[1 * 256 + 4 * l];
        float4 m2 = *(const float4*)&row[2 * 256 + 4 * l];
        float4 m3 = *(const float4*)&row[3 * 256 + 4 * l];
        float q0 = Qs[w * 4 + 0][d];
        float q1 = Qs[w * 4 + 1][d];
        float q2 = Qs[w * 4 + 2][d];
        float q3 = Qs[w * 4 + 3][d];
        fma4(acc[0][0], q0, m0); fma4(acc[0][1], q0, m1); fma4(acc[0][2], q0, m2); fma4(acc[0][3], q0, m3);
        fma4(acc[1][0], q1, m0); fma4(acc[1][1], q1, m1); fma4(acc[1][2], q1, m2); fma4(acc[1][3], q1, m3);
        fma4(acc[2][0], q2, m0); fma4(acc[2][1], q2, m1); fma4(acc[2][2], q2, m2); fma4(acc[2][3], q2, m3);
        fma4(acc[3][0], q3, m0); fma4(acc[3][1], q3, m1); fma4(acc[3][2], q3, m2); fma4(acc[3][3], q3, m3);
    }

#pragma unroll
    for (int r = 0; r < 4; r++) {
        const int s = s0 + w * 4 + r;
        float mx = -3.0e38f;
#pragma unroll
        for (int c = 0; c < 4; c++) {
            float4 v = acc[r][c];
            mx = fmaxf(mx, fmaxf(fmaxf(v.x, v.y), fmaxf(v.z, v.w)));
        }
#pragma unroll
        for (int off = 32; off >= 1; off >>= 1) mx = fmaxf(mx, __shfl_xor(mx, off));
        float sum = 0.f;
#pragma unroll
        for (int c = 0; c < 4; c++) {
            float4 v = acc[r][c];
            v.x = __expf(v.x - mx); v.y = __expf(v.y - mx);
            v.z = __expf(v.z - mx); v.w = __expf(v.w - mx);
            acc[r][c] = v;
            sum += v.x + v.y + v.z + v.w;
        }
#pragma unroll
        for (int off = 32; off >= 1; off >>= 1) sum += __shfl_xor(sum, off);
        const float inv = 1.0f / sum;
        float* out = attn + ((size_t)bh * S + s) * S;
#pragma unroll
        for (int c = 0; c < 4; c++) {
            float4 v = acc[r][c];
            v.x *= inv; v.y *= inv; v.z *= inv; v.w *= inv;
            *(float4*)&out[c * 256 + 4 * l] = v;
        }
    }
}

extern "C" void kernel_launch(void* const* d_in, const int* in_sizes, int n_in,
                              void* d_out, int out_size, void* d_ws, size_t ws_size,
                              hipStream_t stream) {
    const float* Q    = (const float*)d_in[0];
    const float* K    = (const float*)d_in[1];
    const float* V    = (const float*)d_in[2];
    const float* mask = (const float*)d_in[3];
    float* context = (float*)d_out;                          // [bh][S][D]
    float* attn    = (float*)d_out + (size_t)BH * S * D;     // [bh][S][S]

    // workspace: M2T f32 (16.8 MB) + 4 bf16 arrays (8.4 MB each) = 50.4 MB
    float* M2T = (float*)d_ws;
    unsigned short* Kth = (unsigned short*)((char*)d_ws + (size_t)BH * D * S * sizeof(float));
    unsigned short* Ktl = Kth + (size_t)BH * D * S;
    unsigned short* Vth = Ktl + (size_t)BH * D * S;
    unsigned short* Vtl = Vth + (size_t)BH * D * S;

    // 0) K^T, V^T -> bf16 hi/lo
    transpose_split<<<dim3(16, BH, 2), 256, 0, stream>>>(K, V, Kth, Ktl, Vth, Vtl);
    // 1) M2T = (mask @ K)^T per head   (bf16x3 MFMA)
    gemm_mfma<true><<<dim3(16, BH), 256, 0, stream>>>(mask, Kth, Ktl, M2T);
    // 2) attn = softmax(scale * Q @ M2)
    logits_softmax<<<dim3(64, BH), 256, 0, stream>>>(Q, M2T, attn);
    // 3) context = attn @ V            (bf16x3 MFMA)
    gemm_mfma<false><<<dim3(16, BH), 256, 0, stream>>>(attn, Vth, Vtl, context);
}